// Round 11
// baseline (665.283 us; speedup 1.0000x reference)
//
#include <hip/hip_runtime.h>
#include <hip/hip_cooperative_groups.h>

namespace cg = cooperative_groups;

// Attention_85212151153298 — round 11.
// R10 ledger: ~158 us of kernel time vs 248.6 total -> ~90 us of dispatch
// boundaries (7 dispatches). This round: ONE cooperative persistent kernel,
// 512 blocks x 256 thr (2 blocks/CU guaranteed: launch_bounds(256,2) +
// 32 KB LDS), 7 phases separated by grid.sync(). Unlike R9's per-block
// ACQ_REL+fence-during-GEMM disaster, grid sync's acquire-invalidate fires
// once per phase boundary at an idle point. Fallback: if the cooperative
// launch errors (capture/occupancy), run the identical 7-dispatch R10 path.

#define LMBD 0.9f
#define CTXN 4096
#define DIMN 1025
#define DP 1152  // padded DIM, multiple of 128

#define KSPLIT 1024                  // 4 equal splits of 4096
#define PSTRIDE ((size_t)DP * CTXN)  // elements per split-K partial (bf16)

typedef __bf16 bf16x8 __attribute__((ext_vector_type(8)));
typedef float f32x4 __attribute__((ext_vector_type(4)));
typedef long lx2 __attribute__((ext_vector_type(2)));

struct KParams {
  const float *Z, *P, *Q;
  unsigned short *ZbT, *QZT, *XT, *Qb, *Pb;
  float *PZ, *pmax, *psum, *rowmax, *inv_l;
  unsigned char *ET, *PZMb;
  unsigned short *partials;
  float *out;
};

__device__ __forceinline__ unsigned short f2bf(float f) {
  union { float f; unsigned u; } v; v.f = f;
  unsigned r = v.u + 0x7FFFu + ((v.u >> 16) & 1u);  // RNE
  return (unsigned short)(r >> 16);
}
__device__ __forceinline__ float bf2f(unsigned short h) {
  union { unsigned u; float f; } v; v.u = ((unsigned)h) << 16;
  return v.f;
}

__device__ __forceinline__ void gld_lds16(const void* g, void* l) {
  __builtin_amdgcn_global_load_lds(
      (const __attribute__((address_space(1))) unsigned int*)g,
      (__attribute__((address_space(3))) unsigned int*)l, 16, 0, 0);
}

// ---------------- bf16 NT GEMM unit, tile TM x TN, BK=64 -------------------
// LDS rows 128 B = eight 16 B slots; slot s of row r holds k-chunk (s-(r&7))&7
// -> each 8-lane read phase covers all 32 banks once (R10: conflicts 2.3e5).
// MODE 0: bf16 out. MODE 1: f32 out. MODE 4: bf16 out + per-col softmax stats.
template <int MODE, int TM, int TN>
__device__ __forceinline__ void gemm_body(
    char* smem, const unsigned short* __restrict__ A,
    const unsigned short* __restrict__ B, void* __restrict__ Cout, int K, int lda,
    int ldb, int ldc, int bi, int bj, float* __restrict__ pmax,
    float* __restrict__ psum) {
  constexpr int FI = TM / 32, FJ = TN / 32;
  unsigned short* sA = (unsigned short*)smem;
  unsigned short* sB = sA + TM * 64;
  const int tid = threadIdx.x;
  const int wave = tid >> 6;
  const int lane = tid & 63;
  const long i0 = (long)bi * TM;
  const long j0 = (long)bj * TN;
  const int wm = (wave & 1) * (TM / 2);
  const int wn = (wave >> 1) * (TN / 2);

  f32x4 acc[FI][FJ] = {};

  const int srow8 = lane >> 3;              // row within 8-row gld chunk
  const int gk = ((lane & 7) - srow8) & 7;  // staged global k-chunk
  const int mrow = lane & 15;
  const int q2 = lane >> 4;                 // 0..3

  for (int k0 = 0; k0 < K; k0 += 64) {
    __syncthreads();
#pragma unroll
    for (int c = 0; c < TM / 32; ++c) {
      const int q = wave * (TM / 32) + c;
      gld_lds16(A + (i0 + q * 8 + srow8) * (long)lda + k0 + gk * 8, &sA[q * 512]);
    }
#pragma unroll
    for (int c = 0; c < TN / 32; ++c) {
      const int q = wave * (TN / 32) + c;
      gld_lds16(B + (j0 + q * 8 + srow8) * (long)ldb + k0 + gk * 8, &sB[q * 512]);
    }
    __syncthreads();
#pragma unroll
    for (int kk = 0; kk < 2; ++kk) {
      const int slot = ((kk * 4 + q2) + mrow) & 7;
      bf16x8 af[FI], bfr[FJ];
#pragma unroll
      for (int i = 0; i < FI; ++i)
        af[i] = *(const bf16x8*)&sA[(wm + i * 16 + mrow) * 64 + slot * 8];
#pragma unroll
      for (int j = 0; j < FJ; ++j)
        bfr[j] = *(const bf16x8*)&sB[(wn + j * 16 + mrow) * 64 + slot * 8];
#pragma unroll
      for (int i = 0; i < FI; ++i)
#pragma unroll
        for (int j = 0; j < FJ; ++j)
          acc[i][j] =
              __builtin_amdgcn_mfma_f32_16x16x32_bf16(af[i], bfr[j], acc[i][j], 0, 0, 0);
    }
  }

  const int lr = (lane >> 4) * 4;
  const int lc = lane & 15;
#pragma unroll
  for (int i = 0; i < FI; ++i) {
#pragma unroll
    for (int j = 0; j < FJ; ++j) {
#pragma unroll
      for (int r = 0; r < 4; ++r) {
        const long row = i0 + wm + i * 16 + lr + r;
        const long col = j0 + wn + j * 16 + lc;
        const float v = acc[i][j][r];
        if (MODE == 1) ((float*)Cout)[row * ldc + col] = v;
        else ((unsigned short*)Cout)[row * ldc + col] = f2bf(v);
      }
    }
  }

  if constexpr (MODE == 4) {
    float* sMax = (float*)sA;  // [128][8]
    float* sSum = (float*)sB;
    const int k8 = (wave & 1) * 4 + (lane >> 4);
    __syncthreads();
#pragma unroll
    for (int j = 0; j < FJ; ++j) {
      float m = -1e30f;
#pragma unroll
      for (int i = 0; i < FI; ++i)
#pragma unroll
        for (int r = 0; r < 4; ++r) m = fmaxf(m, acc[i][j][r]);
      float sv = 0.f;
#pragma unroll
      for (int i = 0; i < FI; ++i)
#pragma unroll
        for (int r = 0; r < 4; ++r) sv += __expf(acc[i][j][r] - m);
      const int c = wn + j * 16 + lc;
      sMax[c * 8 + k8] = m;
      sSum[c * 8 + k8] = sv;
    }
    __syncthreads();
    if (tid < 128) {
      float m = -1e30f;
#pragma unroll
      for (int k = 0; k < 8; ++k) m = fmaxf(m, sMax[tid * 8 + k]);
      float sv = 0.f;
#pragma unroll
      for (int k = 0; k < 8; ++k) sv += sSum[tid * 8 + k] * __expf(sMax[tid * 8 + k] - m);
      pmax[(size_t)bi * CTXN + j0 + tid] = m;
      psum[(size_t)bi * CTXN + j0 + tid] = sv;
    }
  }
}

// ---- phase units (index mappings identical to R10's grids) ----------------

__device__ __forceinline__ void prep_unit(char* smem, unsigned g, const KParams& a) {
  float* tile = (float*)smem;  // [32][33]
  const int tid = threadIdx.x;
  if (g < 4608) {
    const int n0 = (g & 127) * 32, e0 = (g >> 7) * 32;
    const int tx = tid & 31, ty = tid >> 5;
    __syncthreads();  // LDS reuse across persistent units
#pragma unroll
    for (int k = 0; k < 4; ++k) {
      const int e = e0 + ty + k * 8;
      tile[(ty + k * 8) * 33 + tx] = (e < DIMN) ? a.Z[(size_t)e * CTXN + n0 + tx] : 0.f;
    }
    __syncthreads();
#pragma unroll
    for (int k = 0; k < 4; ++k) {
      const int n = n0 + ty + k * 8;
      a.ZbT[(size_t)n * DP + e0 + tx] = f2bf(tile[tx * 33 + ty + k * 8]);
    }
  } else {
    const unsigned id2 = g - 4608;  // [0, 2592)
    const int mat = id2 >= 1296;
    const float* src = mat ? a.P : a.Q;
    unsigned short* dst = mat ? a.Pb : a.Qb;
    const unsigned e0 = (id2 - (mat ? 1296u : 0u)) * 1024u + tid * 4u;
    const unsigned r = e0 / 1152u;
    const unsigned c = e0 - r * 1152u;
    ushort4 o;
    o.x = (r < DIMN && c + 0 < DIMN) ? f2bf(src[(size_t)r * DIMN + c + 0]) : 0;
    o.y = (r < DIMN && c + 1 < DIMN) ? f2bf(src[(size_t)r * DIMN + c + 1]) : 0;
    o.z = (r < DIMN && c + 2 < DIMN) ? f2bf(src[(size_t)r * DIMN + c + 2]) : 0;
    o.w = (r < DIMN && c + 3 < DIMN) ? f2bf(src[(size_t)r * DIMN + c + 3]) : 0;
    *(ushort4*)&dst[(size_t)r * DP + c] = o;
  }
}

__device__ __forceinline__ void dual_unit(char* smem, unsigned g, const KParams& a) {
  if (g < 576) {
    gemm_body<0, 128, 64>(smem, a.ZbT, a.Qb, a.QZT, DP, DP, DP, DP, g & 31, g >> 5,
                          nullptr, nullptr);
  } else {
    const unsigned h = g - 576;
    gemm_body<1, 64, 128>(smem, a.Pb, a.ZbT, a.PZ, DP, DP, DP, CTXN, h >> 5, h & 31,
                          nullptr, nullptr);
  }
}

__device__ __forceinline__ void xt_unit(char* smem, unsigned u, const KParams& a) {
  gemm_body<4, 128, 128>(smem, a.QZT, a.ZbT, a.XT, DP, DP, DP, CTXN, u & 31, u >> 5,
                         a.pmax, a.psum);
}

__device__ __forceinline__ void red2_unit(unsigned u, const KParams& a) {
  const int n = (int)u * 256 + threadIdx.x;
  float M = -1e30f;
  for (int c = 0; c < 32; ++c) M = fmaxf(M, a.pmax[(size_t)c * CTXN + n]);
  float s = 0.f;
  for (int c = 0; c < 32; ++c)
    s += a.psum[(size_t)c * CTXN + n] * __expf(a.pmax[(size_t)c * CTXN + n] - M);
  a.rowmax[n] = M;
  a.inv_l[n] = 1.0f / (4095.0f * s);
}

__device__ __forceinline__ void ewscan_unit(float* sF, unsigned g, const KParams& a) {
  const int t = threadIdx.x;
  if (g >= 1152) {  // ET[m][n] = fp8(exp(XT - rowmax[n]))
    const size_t idx = ((size_t)(g - 1152) * 256 + t) * 4;
    const ushort4 v = *(const ushort4*)&a.XT[idx];
    const int n = (int)(idx & 4095);
    const float4 rm = *(const float4*)&a.rowmax[n];
    unsigned p = __builtin_amdgcn_cvt_pk_fp8_f32(__expf(bf2f(v.x) - rm.x),
                                                 __expf(bf2f(v.y) - rm.y), 0, false);
    p = __builtin_amdgcn_cvt_pk_fp8_f32(__expf(bf2f(v.z) - rm.z),
                                        __expf(bf2f(v.w) - rm.w), p, true);
    ((unsigned int*)a.ET)[idx >> 2] = p;
    return;
  }
  // suffix lambda-scan of PZ row d -> PZMb = fp8(PZM * inv_l * 256)
  const int d = (int)g;
  const float* row = a.PZ + (size_t)d * CTXN;
  float x[16];
#pragma unroll
  for (int q = 0; q < 4; ++q) {
    const float4 v = *(const float4*)&row[t * 16 + q * 4];
    x[q * 4 + 0] = v.x; x[q * 4 + 1] = v.y; x[q * 4 + 2] = v.z; x[q * 4 + 3] = v.w;
  }
  if (t == 255) x[15] = 0.f;  // last row/col of M are zero
  float loc[16];
  float run = 0.f;
#pragma unroll
  for (int i = 15; i >= 0; --i) { run = run * LMBD + x[i]; loc[i] = run; }
  __syncthreads();  // LDS reuse across persistent units
  float f = loc[0];
  sF[t] = f;
  __syncthreads();
  float mlt = 0.1853020188851841f;  // lambda^16
  for (int step = 1; step < 256; step <<= 1) {
    const float other = (t + step < 256) ? sF[t + step] : 0.f;
    __syncthreads();
    f += mlt * other;
    mlt *= mlt;
    sF[t] = f;
    __syncthreads();
  }
  const float R = (t < 255) ? sF[t + 1] : 0.f;
  float il[16];
#pragma unroll
  for (int q = 0; q < 4; ++q) {
    const float4 v = *(const float4*)&a.inv_l[t * 16 + q * 4];
    il[q * 4 + 0] = v.x * 256.f; il[q * 4 + 1] = v.y * 256.f;
    il[q * 4 + 2] = v.z * 256.f; il[q * 4 + 3] = v.w * 256.f;
  }
  float o[16];
  float p = 1.f;
#pragma unroll
  for (int i = 15; i >= 0; --i) {
    p *= LMBD;
    o[i] = (loc[i] + p * R) * il[i];
  }
  unsigned w[4];
#pragma unroll
  for (int q = 0; q < 4; ++q) {
    unsigned pk = __builtin_amdgcn_cvt_pk_fp8_f32(o[q * 4 + 0], o[q * 4 + 1], 0, false);
    pk = __builtin_amdgcn_cvt_pk_fp8_f32(o[q * 4 + 2], o[q * 4 + 3], pk, true);
    w[q] = pk;
  }
  *(uint4*)&a.PZMb[(size_t)d * CTXN + t * 16] = make_uint4(w[0], w[1], w[2], w[3]);
}

// fp8 split-K GEMM unit (R9/R10: LDS geometry measures 0 bank conflicts).
// g = bj + 32*(bi*4 + bz): ET-strip sharers at stride 32 -> one XCD.
__device__ __forceinline__ void fp8_unit(char* smem, unsigned g, const KParams& a) {
  unsigned char* sA = (unsigned char*)smem;
  unsigned char* sB = sA + 128 * 64;
  const int tid = threadIdx.x;
  const int wave = tid >> 6;
  const int lane = tid & 63;
  const unsigned bj = g & 31;
  const unsigned t = g >> 5;  // 0..35
  const unsigned bi = t >> 2;
  const unsigned bz = t & 3;
  const long i0 = (long)bi * 128;
  const long j0 = (long)bj * 128;
  const int wm = (wave & 1) * 64;
  const int wn = (wave >> 1) * 64;
  const int kb = bz * KSPLIT;
  unsigned short* Cout = a.partials + (size_t)bz * PSTRIDE;

  f32x4 acc[4][4] = {};
  const int srow = lane >> 2;
  const int skc = (((lane & 3) - (lane >> 3)) & 3) * 16;  // swizzled 16B slot
  const int mrow = lane & 15;
  const int slot = ((((lane >> 4) + (mrow >> 1)) & 3)) * 16;

  for (int k0 = kb; k0 < kb + KSPLIT; k0 += 64) {
    __syncthreads();
#pragma unroll
    for (int c = 0; c < 2; ++c) {
      const int q = wave * 2 + c;
      gld_lds16(a.PZMb + (i0 + q * 16 + srow) * (long)CTXN + k0 + skc, &sA[q * 1024]);
      gld_lds16(a.ET + (j0 + q * 16 + srow) * (long)CTXN + k0 + skc, &sB[q * 1024]);
    }
    __syncthreads();
    lx2 af[4], bfr[4];
#pragma unroll
    for (int i = 0; i < 4; ++i)
      af[i] = *(const lx2*)&sA[(wm + i * 16 + mrow) * 64 + slot];
#pragma unroll
    for (int j = 0; j < 4; ++j)
      bfr[j] = *(const lx2*)&sB[(wn + j * 16 + mrow) * 64 + slot];
#pragma unroll
    for (int i = 0; i < 4; ++i)
#pragma unroll
      for (int j = 0; j < 4; ++j) {
        acc[i][j] = __builtin_amdgcn_mfma_f32_16x16x32_fp8_fp8(af[i].x, bfr[j].x,
                                                               acc[i][j], 0, 0, 0);
        acc[i][j] = __builtin_amdgcn_mfma_f32_16x16x32_fp8_fp8(af[i].y, bfr[j].y,
                                                               acc[i][j], 0, 0, 0);
      }
  }

  const int lr = (lane >> 4) * 4;
  const int lc = lane & 15;
#pragma unroll
  for (int i = 0; i < 4; ++i)
#pragma unroll
    for (int j = 0; j < 4; ++j)
#pragma unroll
      for (int r = 0; r < 4; ++r) {
        const long row = i0 + wm + i * 16 + lr + r;
        if (row < DIMN)
          Cout[row * (long)CTXN + j0 + wn + j * 16 + lc] = f2bf(acc[i][j][r]);
      }
}

__device__ __forceinline__ void reduce_unit(unsigned u, const KParams& a) {
  const size_t idx = ((size_t)u * 256 + threadIdx.x) * 4;
  float ax = 0.f, ay = 0.f, az = 0.f, aw = 0.f;
#pragma unroll
  for (int z = 0; z < 4; ++z) {
    const ushort4 v = *(const ushort4*)&a.partials[(size_t)z * PSTRIDE + idx];
    ax += bf2f(v.x); ay += bf2f(v.y); az += bf2f(v.z); aw += bf2f(v.w);
  }
  const f32x4 zv = *(const f32x4*)&a.Z[idx];
  f32x4 o;
  o[0] = zv[0] + ax * 0.00390625f;
  o[1] = zv[1] + ay * 0.00390625f;
  o[2] = zv[2] + az * 0.00390625f;
  o[3] = zv[3] + aw * 0.00390625f;
  *(f32x4*)&a.out[idx] = o;
}

// ---------------- the cooperative mega-kernel ------------------------------
__global__ __launch_bounds__(256, 2) void mega(KParams a) {
  __shared__ __align__(16) char smem[32768];
  cg::grid_group grid = cg::this_grid();
  const unsigned nb = gridDim.x;
  const unsigned b0 = blockIdx.x;

  for (unsigned u = b0; u < 7200; u += nb) prep_unit(smem, u, a);
  grid.sync();
  for (unsigned u = b0; u < 1152; u += nb) dual_unit(smem, u, a);
  grid.sync();
  for (unsigned u = b0; u < 1024; u += nb) xt_unit(smem, u, a);
  grid.sync();
  for (unsigned u = b0; u < 16; u += nb) red2_unit(u, a);
  grid.sync();
  for (unsigned u = b0; u < 17536; u += nb) ewscan_unit((float*)smem, u, a);
  grid.sync();
  for (unsigned u = b0; u < 1152; u += nb) fp8_unit(smem, u, a);
  grid.sync();
  for (unsigned u = b0; u < 4100; u += nb) reduce_unit(u, a);
}

// ---------------- fallback wrappers (exact R10 pipeline) -------------------
__global__ void prep_k(KParams a) {
  __shared__ __align__(16) char smem[4352];
  prep_unit(smem, blockIdx.x, a);
}
__global__ __launch_bounds__(256, 2) void dual_k(KParams a) {
  __shared__ __align__(16) char smem[24576];
  dual_unit(smem, blockIdx.x, a);
}
__global__ __launch_bounds__(256, 2) void xt_k(KParams a) {
  __shared__ __align__(16) char smem[32768];
  xt_unit(smem, blockIdx.x, a);
}
__global__ void red2_k(KParams a) { red2_unit(blockIdx.x, a); }
__global__ __launch_bounds__(256) void ewscan_k(KParams a) {
  __shared__ float sF[256];
  ewscan_unit(sF, blockIdx.x, a);
}
__global__ __launch_bounds__(256, 2) void fp8_k(KParams a) {
  __shared__ __align__(16) char smem[16384];
  fp8_unit(smem, blockIdx.x, a);
}
__global__ void reduce_k(KParams a) { reduce_unit(blockIdx.x, a); }

extern "C" void kernel_launch(void* const* d_in, const int* in_sizes, int n_in,
                              void* d_out, int out_size, void* d_ws, size_t ws_size,
                              hipStream_t stream) {
  KParams a;
  a.Z = (const float*)d_in[0];
  a.P = (const float*)d_in[1];
  a.Q = (const float*)d_in[2];
  // d_in[3] = M: reproduced analytically by the scan.

  char* ws = (char*)d_ws;
  size_t off = 0;
  auto alloc = [&](size_t bytes) {
    void* p = ws + off;
    off += (bytes + 255) & ~(size_t)255;
    return p;
  };
  a.ET     = (unsigned char*)alloc((size_t)CTXN * CTXN);  // fp8
  a.PZMb   = (unsigned char*)alloc((size_t)DP * CTXN);    // fp8 x256
  a.rowmax = (float*)alloc((size_t)CTXN * 4);
  a.inv_l  = (float*)alloc((size_t)CTXN * 4);
  // pool — ZbT/QZT/XT dead before the fp8 GEMM; bf16 partials (37.7 MB)
  // overlay them (52.4 MB). PZ untouched.
  char* pool = (char*)alloc(0);
  a.ZbT  = (unsigned short*)alloc((size_t)CTXN * DP * 2);
  a.QZT  = (unsigned short*)alloc((size_t)CTXN * DP * 2);
  a.XT   = (unsigned short*)alloc((size_t)CTXN * CTXN * 2);
  a.PZ   = (float*)alloc((size_t)DP * CTXN * 4);
  a.Qb   = (unsigned short*)alloc((size_t)DP * DP * 2);
  a.Pb   = (unsigned short*)alloc((size_t)DP * DP * 2);
  a.pmax = (float*)alloc((size_t)32 * CTXN * 4);
  a.psum = (float*)alloc((size_t)32 * CTXN * 4);
  a.partials = (unsigned short*)pool;
  a.out = (float*)d_out;
  if (off > ws_size) return;

  void* kargs[] = {(void*)&a};
  hipError_t err =
      hipLaunchCooperativeKernel(mega, dim3(512), dim3(256), kargs, 0u, stream);
  if (err != hipSuccess) {
    (void)hipGetLastError();  // clear sticky error; run the R10 path instead
    prep_k<<<7200, 256, 0, stream>>>(a);
    dual_k<<<1152, 256, 0, stream>>>(a);
    xt_k<<<1024, 256, 0, stream>>>(a);
    red2_k<<<16, 256, 0, stream>>>(a);
    ewscan_k<<<17536, 256, 0, stream>>>(a);
    fp8_k<<<1152, 256, 0, stream>>>(a);
    reduce_k<<<4100, 256, 0, stream>>>(a);
  }
}

// Round 12
// 241.355 us; speedup vs baseline: 2.7564x; 2.7564x over previous
//
#include <hip/hip_runtime.h>

// Attention_85212151153298 — round 12.
// = R10 (best: 248.6 us) + dead-work trims. R11 post-mortem: cooperative
// mega-kernel ran 573 us (MfmaUtil 7%) — persistent phases + grid.sync
// degrade GEMMs far more than dispatch boundaries cost. R10 architecture
// stands. Trims (all provably-zero padded range e/d in [1025,1152)):
// K 1152 -> 1088 in dual/xt; dual d-tiles 18 -> 17 per half; scan rows
// -> 1088; prep Z-transpose 36 -> 34 e-tiles. PZMb rows 1088-1151 are
// garbage but row-independent in MFMA and masked at store (fp8 has no Inf).

#define LMBD 0.9f
#define CTXN 4096
#define DIMN 1025
#define DP 1152   // padded leading-dim stride (unchanged)
#define KE 1088   // trimmed K for the e-dimension: 17*64 >= 1025

#define KSPLIT 1024                  // 4 equal splits of 4096
#define PSTRIDE ((size_t)DP * CTXN)  // elements per split-K partial (bf16)

typedef __bf16 bf16x8 __attribute__((ext_vector_type(8)));
typedef float f32x4 __attribute__((ext_vector_type(4)));
typedef long lx2 __attribute__((ext_vector_type(2)));

__device__ __forceinline__ unsigned short f2bf(float f) {
  union { float f; unsigned u; } v; v.f = f;
  unsigned r = v.u + 0x7FFFu + ((v.u >> 16) & 1u);  // RNE
  return (unsigned short)(r >> 16);
}
__device__ __forceinline__ float bf2f(unsigned short h) {
  union { unsigned u; float f; } v; v.u = ((unsigned)h) << 16;
  return v.f;
}

__device__ __forceinline__ void gld_lds16(const void* g, void* l) {
  __builtin_amdgcn_global_load_lds(
      (const __attribute__((address_space(1))) unsigned int*)g,
      (__attribute__((address_space(3))) unsigned int*)l, 16, 0, 0);
}

// ---------------- bf16 NT GEMM body, tile TM x TN, BK=64 -------------------
// C[i,j] = sum_k A[i,k]*B[j,k]; A:(M,K), B:(N,K) bf16 row-major.
// LDS rows 128 B = eight 16 B slots; slot s of row r holds global k-chunk
// (s - (r&7)) & 7 -> each 8-lane read phase covers all 32 banks exactly once
// (R10: conflicts 4.9e6 -> 2.3e5).
// MODE 0: bf16 out. MODE 1: f32 out. MODE 4 (128x128): bf16 out + per-col
// softmax partial stats over the block's 128 rows.
template <int MODE, int TM, int TN>
__device__ __forceinline__ void gemm_body(
    const unsigned short* __restrict__ A, const unsigned short* __restrict__ B,
    void* __restrict__ Cout, int K, int lda, int ldb, int ldc, int bi, int bj,
    float* __restrict__ pmax, float* __restrict__ psum) {
  constexpr int FI = TM / 32, FJ = TN / 32;  // frags per wave
  __shared__ unsigned short sA[TM * 64];
  __shared__ unsigned short sB[TN * 64];
  const int tid = threadIdx.x;
  const int wave = tid >> 6;
  const int lane = tid & 63;
  const long i0 = (long)bi * TM;
  const long j0 = (long)bj * TN;
  const int wm = (wave & 1) * (TM / 2);
  const int wn = (wave >> 1) * (TN / 2);

  f32x4 acc[FI][FJ] = {};

  const int srow8 = lane >> 3;              // row within 8-row gld chunk
  const int gk = ((lane & 7) - srow8) & 7;  // staged global k-chunk
  const int mrow = lane & 15;
  const int q2 = lane >> 4;                 // 0..3

  for (int k0 = 0; k0 < K; k0 += 64) {
    __syncthreads();
#pragma unroll
    for (int c = 0; c < TM / 32; ++c) {
      const int q = wave * (TM / 32) + c;
      gld_lds16(A + (i0 + q * 8 + srow8) * (long)lda + k0 + gk * 8, &sA[q * 512]);
    }
#pragma unroll
    for (int c = 0; c < TN / 32; ++c) {
      const int q = wave * (TN / 32) + c;
      gld_lds16(B + (j0 + q * 8 + srow8) * (long)ldb + k0 + gk * 8, &sB[q * 512]);
    }
    __syncthreads();
#pragma unroll
    for (int kk = 0; kk < 2; ++kk) {
      const int slot = ((kk * 4 + q2) + mrow) & 7;
      bf16x8 af[FI], bfr[FJ];
#pragma unroll
      for (int i = 0; i < FI; ++i)
        af[i] = *(const bf16x8*)&sA[(wm + i * 16 + mrow) * 64 + slot * 8];
#pragma unroll
      for (int j = 0; j < FJ; ++j)
        bfr[j] = *(const bf16x8*)&sB[(wn + j * 16 + mrow) * 64 + slot * 8];
#pragma unroll
      for (int i = 0; i < FI; ++i)
#pragma unroll
        for (int j = 0; j < FJ; ++j)
          acc[i][j] =
              __builtin_amdgcn_mfma_f32_16x16x32_bf16(af[i], bfr[j], acc[i][j], 0, 0, 0);
    }
  }

  const int lr = (lane >> 4) * 4;
  const int lc = lane & 15;
#pragma unroll
  for (int i = 0; i < FI; ++i) {
#pragma unroll
    for (int j = 0; j < FJ; ++j) {
#pragma unroll
      for (int r = 0; r < 4; ++r) {
        const long row = i0 + wm + i * 16 + lr + r;
        const long col = j0 + wn + j * 16 + lc;
        const float v = acc[i][j][r];
        if (MODE == 1) ((float*)Cout)[row * ldc + col] = v;
        else ((unsigned short*)Cout)[row * ldc + col] = f2bf(v);
      }
    }
  }

  if constexpr (MODE == 4) {
    float* sMax = (float*)sA;  // [128][8]
    float* sSum = (float*)sB;
    const int k8 = (wave & 1) * 4 + (lane >> 4);
    __syncthreads();
#pragma unroll
    for (int j = 0; j < FJ; ++j) {
      float m = -1e30f;
#pragma unroll
      for (int i = 0; i < FI; ++i)
#pragma unroll
        for (int r = 0; r < 4; ++r) m = fmaxf(m, acc[i][j][r]);
      float sv = 0.f;
#pragma unroll
      for (int i = 0; i < FI; ++i)
#pragma unroll
        for (int r = 0; r < 4; ++r) sv += __expf(acc[i][j][r] - m);
      const int c = wn + j * 16 + lc;
      sMax[c * 8 + k8] = m;
      sSum[c * 8 + k8] = sv;
    }
    __syncthreads();
    if (tid < 128) {
      float m = -1e30f;
#pragma unroll
      for (int k = 0; k < 8; ++k) m = fmaxf(m, sMax[tid * 8 + k]);
      float sv = 0.f;
#pragma unroll
      for (int k = 0; k < 8; ++k) sv += sSum[tid * 8 + k] * __expf(sMax[tid * 8 + k] - m);
      pmax[(size_t)bi * CTXN + j0 + tid] = m;
      psum[(size_t)bi * CTXN + j0 + tid] = sv;
    }
  }
}

// XT[m,n] = sum_d QZT[m,d]*ZbT[n,d] (K=1088) + per-col stats. grid (32,32).
__global__ __launch_bounds__(256, 2) void gemm_xt(
    const unsigned short* __restrict__ QZT, const unsigned short* __restrict__ ZbT,
    unsigned short* __restrict__ XT, float* __restrict__ pmax,
    float* __restrict__ psum) {
  gemm_body<4, 128, 128>(QZT, ZbT, XT, KE, DP, DP, CTXN, blockIdx.x, blockIdx.y, pmax,
                         psum);
}

// Merged QZT + PZ dispatch, 1088 blocks, K=1088, 17 d-tiles per half.
__global__ __launch_bounds__(256, 2) void gemm_dual(
    const unsigned short* __restrict__ ZbT, const unsigned short* __restrict__ Qb,
    unsigned short* __restrict__ QZT, const unsigned short* __restrict__ Pb,
    float* __restrict__ PZ) {
  const unsigned g = blockIdx.x;
  if (g < 544) {
    gemm_body<0, 128, 64>(ZbT, Qb, QZT, KE, DP, DP, DP, g & 31, g >> 5, nullptr,
                          nullptr);
  } else {
    const unsigned h = g - 544;
    gemm_body<1, 64, 128>(Pb, ZbT, PZ, KE, DP, DP, CTXN, h >> 5, h & 31, nullptr,
                          nullptr);
  }
}

// ---------------- fp8 NT split-K GEMM (final), BK=64, bf16 partials --------
// A: PZMb (fp8, x256), B: ET (fp8). Partials bf16 (x256), rows < 1025 only.
// grid g = bj + 32*(bi*4 + bz): ET-strip sharers at stride 32 (= 0 mod 8)
// -> one XCD. (R9/R10: 0 LDS bank conflicts.) PZMb rows >= 1088 are garbage
// but accumulate only into discarded (masked) output rows.
__global__ __launch_bounds__(256, 2) void gemm_fp8_splitk(
    const unsigned char* __restrict__ A, const unsigned char* __restrict__ B,
    unsigned short* __restrict__ Cout) {
  __shared__ unsigned char sA[128 * 64];
  __shared__ unsigned char sB[128 * 64];
  const int tid = threadIdx.x;
  const int wave = tid >> 6;
  const int lane = tid & 63;
  const unsigned g = blockIdx.x;
  const unsigned bj = g & 31;
  const unsigned t = g >> 5;  // 0..35
  const unsigned bi = t >> 2;
  const unsigned bz = t & 3;
  const long i0 = (long)bi * 128;
  const long j0 = (long)bj * 128;
  const int wm = (wave & 1) * 64;
  const int wn = (wave >> 1) * 64;
  const int kb = bz * KSPLIT;
  Cout += (size_t)bz * PSTRIDE;

  f32x4 acc[4][4] = {};
  const int srow = lane >> 2;
  const int skc = (((lane & 3) - (lane >> 3)) & 3) * 16;  // swizzled 16B slot
  const int mrow = lane & 15;
  const int slot = ((((lane >> 4) + (mrow >> 1)) & 3)) * 16;

  for (int k0 = kb; k0 < kb + KSPLIT; k0 += 64) {
    __syncthreads();
#pragma unroll
    for (int c = 0; c < 2; ++c) {
      const int q = wave * 2 + c;
      gld_lds16(A + (i0 + q * 16 + srow) * (long)CTXN + k0 + skc, &sA[q * 1024]);
      gld_lds16(B + (j0 + q * 16 + srow) * (long)CTXN + k0 + skc, &sB[q * 1024]);
    }
    __syncthreads();
    lx2 af[4], bfr[4];
#pragma unroll
    for (int i = 0; i < 4; ++i)
      af[i] = *(const lx2*)&sA[(wm + i * 16 + mrow) * 64 + slot];
#pragma unroll
    for (int j = 0; j < 4; ++j)
      bfr[j] = *(const lx2*)&sB[(wn + j * 16 + mrow) * 64 + slot];
#pragma unroll
    for (int i = 0; i < 4; ++i)
#pragma unroll
      for (int j = 0; j < 4; ++j) {
        acc[i][j] = __builtin_amdgcn_mfma_f32_16x16x32_fp8_fp8(af[i].x, bfr[j].x,
                                                               acc[i][j], 0, 0, 0);
        acc[i][j] = __builtin_amdgcn_mfma_f32_16x16x32_fp8_fp8(af[i].y, bfr[j].y,
                                                               acc[i][j], 0, 0, 0);
      }
  }

  const int lr = (lane >> 4) * 4;
  const int lc = lane & 15;
#pragma unroll
  for (int i = 0; i < 4; ++i)
#pragma unroll
    for (int j = 0; j < 4; ++j)
#pragma unroll
      for (int r = 0; r < 4; ++r) {
        const long row = i0 + wm + i * 16 + lr + r;
        if (row < DIMN)
          Cout[row * (long)CTXN + j0 + wn + j * 16 + lc] = f2bf(acc[i][j][r]);
      }
}

// out[r,c] = Z[r,c] + (sum of 4 bf16 partials)/256, 4100 blocks
__global__ void reduce_kernel(const unsigned short* __restrict__ Pt,
                              const float* __restrict__ Z, float* __restrict__ out) {
  const size_t idx = ((size_t)blockIdx.x * 256 + threadIdx.x) * 4;
  float ax = 0.f, ay = 0.f, az = 0.f, aw = 0.f;
#pragma unroll
  for (int z = 0; z < 4; ++z) {
    const ushort4 v = *(const ushort4*)&Pt[(size_t)z * PSTRIDE + idx];
    ax += bf2f(v.x); ay += bf2f(v.y); az += bf2f(v.z); aw += bf2f(v.w);
  }
  const f32x4 zv = *(const f32x4*)&Z[idx];
  f32x4 o;
  o[0] = zv[0] + ax * 0.00390625f;
  o[1] = zv[1] + ay * 0.00390625f;
  o[2] = zv[2] + az * 0.00390625f;
  o[3] = zv[3] + aw * 0.00390625f;
  *(f32x4*)&out[idx] = o;
}

// Merged prep: ids [0,4352) transpose Z -> ZbT (e < 1088 only; rest unused);
// ids [4352, 6944) pad Q/P -> Qb/Pb bf16 (full 1152x1152, zeros outside).
__global__ void prep_kernel(const float* __restrict__ Z, const float* __restrict__ Q,
                            const float* __restrict__ P,
                            unsigned short* __restrict__ ZbT,
                            unsigned short* __restrict__ Qb,
                            unsigned short* __restrict__ Pb) {
  __shared__ float tile[32][33];
  const unsigned g = blockIdx.x;
  const int tid = threadIdx.x;
  if (g < 4352) {
    const int n0 = (g & 127) * 32, e0 = (g >> 7) * 32;  // e0 < 1088
    const int tx = tid & 31, ty = tid >> 5;
#pragma unroll
    for (int k = 0; k < 4; ++k) {
      const int e = e0 + ty + k * 8;
      tile[ty + k * 8][tx] = (e < DIMN) ? Z[(size_t)e * CTXN + n0 + tx] : 0.f;
    }
    __syncthreads();
#pragma unroll
    for (int k = 0; k < 4; ++k) {
      const int n = n0 + ty + k * 8;
      ZbT[(size_t)n * DP + e0 + tx] = f2bf(tile[tx][ty + k * 8]);
    }
  } else {
    const unsigned id2 = g - 4352;  // [0, 2592)
    const int mat = id2 >= 1296;
    const float* src = mat ? P : Q;
    unsigned short* dst = mat ? Pb : Qb;
    const unsigned e0 = (id2 - (mat ? 1296u : 0u)) * 1024u + tid * 4u;
    const unsigned r = e0 / 1152u;
    const unsigned c = e0 - r * 1152u;
    ushort4 o;
    o.x = (r < DIMN && c + 0 < DIMN) ? f2bf(src[(size_t)r * DIMN + c + 0]) : 0;
    o.y = (r < DIMN && c + 1 < DIMN) ? f2bf(src[(size_t)r * DIMN + c + 1]) : 0;
    o.z = (r < DIMN && c + 2 < DIMN) ? f2bf(src[(size_t)r * DIMN + c + 2]) : 0;
    o.w = (r < DIMN && c + 3 < DIMN) ? f2bf(src[(size_t)r * DIMN + c + 3]) : 0;
    *(ushort4*)&dst[(size_t)r * DP + c] = o;
  }
}

// merge 32 chunk stats -> rowmax[n], inv_l[n] = 1/(N*l[n])
__global__ void red2_kernel(const float* __restrict__ pmax, const float* __restrict__ psum,
                            float* __restrict__ rowmax, float* __restrict__ inv_l) {
  const int n = blockIdx.x * 256 + threadIdx.x;
  float M = -1e30f;
  for (int c = 0; c < 32; ++c) M = fmaxf(M, pmax[(size_t)c * CTXN + n]);
  float s = 0.f;
  for (int c = 0; c < 32; ++c)
    s += psum[(size_t)c * CTXN + n] * __expf(pmax[(size_t)c * CTXN + n] - M);
  rowmax[n] = M;
  inv_l[n] = 1.0f / (4095.0f * s);
}

// Merged ew + scan. ids [0,1088): suffix lambda-scan of PZ row d -> PZMb fp8 x256.
// ids [1088, 17472): ET[m][n] = fp8(exp(XT[m][n] - rowmax[n])).
__global__ __launch_bounds__(256) void ewscan_kernel(
    const unsigned short* __restrict__ XT, const float* __restrict__ rowmax,
    unsigned int* __restrict__ ET, const float* __restrict__ PZ,
    const float* __restrict__ inv_l, unsigned char* __restrict__ PZMb) {
  __shared__ float sF[256];
  const unsigned g = blockIdx.x;
  const int t = threadIdx.x;
  if (g >= 1088) {
    const size_t idx = ((size_t)(g - 1088) * 256 + t) * 4;
    const ushort4 v = *(const ushort4*)&XT[idx];
    const int n = (int)(idx & 4095);
    const float4 rm = *(const float4*)&rowmax[n];
    unsigned p = __builtin_amdgcn_cvt_pk_fp8_f32(__expf(bf2f(v.x) - rm.x),
                                                 __expf(bf2f(v.y) - rm.y), 0, false);
    p = __builtin_amdgcn_cvt_pk_fp8_f32(__expf(bf2f(v.z) - rm.z),
                                        __expf(bf2f(v.w) - rm.w), p, true);
    ET[idx >> 2] = p;
    return;
  }
  const int d = g;
  const float* row = PZ + (size_t)d * CTXN;
  float x[16];
#pragma unroll
  for (int q = 0; q < 4; ++q) {
    const float4 v = *(const float4*)&row[t * 16 + q * 4];
    x[q * 4 + 0] = v.x; x[q * 4 + 1] = v.y; x[q * 4 + 2] = v.z; x[q * 4 + 3] = v.w;
  }
  if (t == 255) x[15] = 0.f;  // last row/col of M are zero
  float loc[16];
  float run = 0.f;
#pragma unroll
  for (int i = 15; i >= 0; --i) { run = run * LMBD + x[i]; loc[i] = run; }
  float f = loc[0];
  sF[t] = f;
  __syncthreads();
  float mlt = 0.1853020188851841f;  // lambda^16
  for (int step = 1; step < 256; step <<= 1) {
    const float other = (t + step < 256) ? sF[t + step] : 0.f;
    __syncthreads();
    f += mlt * other;
    mlt *= mlt;
    sF[t] = f;
    __syncthreads();
  }
  const float R = (t < 255) ? sF[t + 1] : 0.f;
  float il[16];
#pragma unroll
  for (int q = 0; q < 4; ++q) {
    const float4 v = *(const float4*)&inv_l[t * 16 + q * 4];
    il[q * 4 + 0] = v.x * 256.f; il[q * 4 + 1] = v.y * 256.f;
    il[q * 4 + 2] = v.z * 256.f; il[q * 4 + 3] = v.w * 256.f;
  }
  float o[16];
  float p = 1.f;
#pragma unroll
  for (int i = 15; i >= 0; --i) {
    p *= LMBD;
    o[i] = (loc[i] + p * R) * il[i];
  }
  unsigned w[4];
#pragma unroll
  for (int q = 0; q < 4; ++q) {
    unsigned pk = __builtin_amdgcn_cvt_pk_fp8_f32(o[q * 4 + 0], o[q * 4 + 1], 0, false);
    pk = __builtin_amdgcn_cvt_pk_fp8_f32(o[q * 4 + 2], o[q * 4 + 3], pk, true);
    w[q] = pk;
  }
  *(uint4*)&PZMb[(size_t)d * CTXN + t * 16] = make_uint4(w[0], w[1], w[2], w[3]);
}

extern "C" void kernel_launch(void* const* d_in, const int* in_sizes, int n_in,
                              void* d_out, int out_size, void* d_ws, size_t ws_size,
                              hipStream_t stream) {
  const float* Z = (const float*)d_in[0];
  const float* P = (const float*)d_in[1];
  const float* Q = (const float*)d_in[2];
  // d_in[3] = M: reproduced analytically by the scan.

  char* ws = (char*)d_ws;
  size_t off = 0;
  auto alloc = [&](size_t bytes) {
    void* p = ws + off;
    off += (bytes + 255) & ~(size_t)255;
    return p;
  };
  // persistent through the final GEMM:
  unsigned char* ET   = (unsigned char*)alloc((size_t)CTXN * CTXN);  // fp8
  unsigned char* PZMb = (unsigned char*)alloc((size_t)DP * CTXN);    // fp8 x256
  float* rowmax       = (float*)alloc((size_t)CTXN * 4);
  float* inv_l        = (float*)alloc((size_t)CTXN * 4);
  // pool — ZbT/QZT/XT are dead before the fp8 GEMM; its bf16 partial buffer
  // (4*DP*CTXN*2 = 37.7 MB) overlays them (52.4 MB). PZ untouched.
  char* pool = (char*)alloc(0);
  unsigned short* ZbT = (unsigned short*)alloc((size_t)CTXN * DP * 2);
  unsigned short* QZT = (unsigned short*)alloc((size_t)CTXN * DP * 2);
  unsigned short* XT  = (unsigned short*)alloc((size_t)CTXN * CTXN * 2);
  float* PZ           = (float*)alloc((size_t)DP * CTXN * 4);
  unsigned short* Qb  = (unsigned short*)alloc((size_t)DP * DP * 2);
  unsigned short* Pb  = (unsigned short*)alloc((size_t)DP * DP * 2);
  float* pmax         = (float*)alloc((size_t)32 * CTXN * 4);
  float* psum         = (float*)alloc((size_t)32 * CTXN * 4);
  unsigned short* partials = (unsigned short*)pool;
  if (off > ws_size) return;

  // Z transpose (e < 1088) + Q/P pad, one dispatch
  prep_kernel<<<6944, 256, 0, stream>>>(Z, Q, P, ZbT, Qb, Pb);

  // QZT[m,d] and PZ[d,n] in one dispatch, K=1088, 17 d-tiles per half
  gemm_dual<<<1088, 256, 0, stream>>>(ZbT, Qb, QZT, Pb, PZ);

  // XT[m,n] = sum_d QZT[m,d] * ZbT[n,d], K=1088; epilogue: per-col stats
  gemm_xt<<<dim3(32, 32), 256, 0, stream>>>(QZT, ZbT, XT, pmax, psum);

  red2_kernel<<<16, 256, 0, stream>>>(pmax, psum, rowmax, inv_l);

  // scan (PZ rows < 1088 -> PZMb fp8 x256) + ew (XT -> ET fp8), one dispatch
  ewscan_kernel<<<17472, 256, 0, stream>>>(XT, rowmax, (unsigned int*)ET, PZ, inv_l,
                                           PZMb);

  // partial[z][d,m] = sum_{n in split z} PZMb[d,n] * ET[m,n]   (x256, bf16)
  gemm_fp8_splitk<<<1152, 256, 0, stream>>>(PZMb, ET, partials);
  // out = Z + (p0+..+p3)/256 (rows < 1025)
  reduce_kernel<<<4100, 256, 0, stream>>>(partials, Z, (float*)d_out);
}